// Round 1
// 1146.232 us; speedup vs baseline: 1.2379x; 1.2379x over previous
//
#include <hip/hip_runtime.h>

// IndexedDense: out[b] = relu(x[b] @ ws[idx[b]] + bs[idx[b]])
// B=64, S=512, D=1024, U=4096, E=16.  fp32 in/out, fp16 MFMA internally.
//
// Fast path (needs ~193 MiB workspace, checked at runtime):
//   1. perm_kernel    : sort batches by expert (L2 locality) + used-expert mask
//   2. convert_x      : x fp32 -> fp16                (k-contiguous already)
//   3. transpose_w    : ws[e][d][u] fp32 -> wt[e][u][d] fp16  (makes B k-contiguous)
//   4. indexed_dense_gemm_h : pure-fp16 GEMM, global_load_lds staging,
//      double-buffered LDS, ONE barrier per K-tile (T3 minimum 2-phase template).
// Fallback path: previous kernel (reg-staged fp32->fp16 in-loop) if ws too small.

typedef float v4f  __attribute__((ext_vector_type(4)));
typedef _Float16 v8h __attribute__((ext_vector_type(8)));
typedef __fp16  v2fp __attribute__((ext_vector_type(2)));   // cvt_pkrtz return type

constexpr int Bb = 64, Ss = 512, Dd = 1024, Uu = 4096, Ee = 16;
constexpr int BM = 128, BN = 128, BK = 32;
constexpr int KT = Dd / BK;        // 32 k-tiles
constexpr int BKP = 40;            // fallback path LDS pitch

// ---------------------------------------------------------------------------
// async global->LDS, 16B per lane.  LDS dest is wave-uniform base + lane*16.
typedef const __attribute__((address_space(1))) void gvoid_t;
typedef __attribute__((address_space(3))) void lvoid_t;
__device__ __forceinline__ void gl2lds16(const void* g, void* l) {
  __builtin_amdgcn_global_load_lds((gvoid_t*)g, (lvoid_t*)l, 16, 0, 0);
}

// ---------------------------------------------------------------------------
// Sort batches by expert so consecutive blockIdx.z share the same w panel.
// Also emits used[e] so transpose_w can skip unreferenced experts.
__global__ void perm_kernel(const int* __restrict__ index, int* __restrict__ perm,
                            int* __restrict__ used) {
  const int b = threadIdx.x;        // 64 threads
  const int e = index[b];
  int pos = 0;
  for (int b2 = 0; b2 < Bb; ++b2) {
    const int e2 = index[b2];
    pos += (e2 < e) || (e2 == e && b2 < b);
  }
  perm[pos] = b;
  if (used != nullptr && b < Ee) {
    int u = 0;
    for (int b2 = 0; b2 < Bb; ++b2) u |= (index[b2] == b) ? 1 : 0;
    used[b] = u;
  }
}

// ---------------------------------------------------------------------------
// x fp32 -> fp16, vectorized 8 elems/thread (32B in, 16B out).
__global__ __launch_bounds__(256) void convert_x(const float* __restrict__ in,
                                                 _Float16* __restrict__ outh) {
  const size_t i = ((size_t)blockIdx.x * 256 + threadIdx.x) * 8;
  const v4f a = *(const v4f*)(in + i);
  const v4f b = *(const v4f*)(in + i + 4);
  v8h h;
  #pragma unroll
  for (int j = 0; j < 4; ++j) h[j] = (_Float16)a[j];
  #pragma unroll
  for (int j = 0; j < 4; ++j) h[4 + j] = (_Float16)b[j];
  *(v8h*)(outh + i) = h;
}

// ---------------------------------------------------------------------------
// ws[e][d][u] fp32 -> wt[e][u][d] fp16.  64x64 tile via LDS, coalesced both sides.
__global__ __launch_bounds__(256) void transpose_w(const float* __restrict__ ws,
                                                   _Float16* __restrict__ wt,
                                                   const int* __restrict__ used) {
  const int e = blockIdx.z;
  if (!used[e]) return;
  const int u0 = blockIdx.x * 64;   // U/64 = 64
  const int d0 = blockIdx.y * 64;   // D/64 = 16
  __shared__ float tile[64][65];
  const int tid = threadIdx.x;
  // load: rows d, float4 along u (coalesced)
  {
    const int tu = (tid & 15) * 4;
    const int td = tid >> 4;        // 0..15
    const float* src = ws + (size_t)e * Dd * Uu + (size_t)d0 * Uu + u0;
    #pragma unroll
    for (int i = 0; i < 4; ++i) {
      const v4f v = *(const v4f*)(src + (size_t)(td + i * 16) * Uu + tu);
      tile[td + i * 16][tu + 0] = v[0];
      tile[td + i * 16][tu + 1] = v[1];
      tile[td + i * 16][tu + 2] = v[2];
      tile[td + i * 16][tu + 3] = v[3];
    }
  }
  __syncthreads();
  // store: rows u, 16 fp16 along d per thread (2x b128, coalesced)
  {
    const int tu = tid >> 2;          // 0..63
    const int tq = (tid & 3) * 16;    // d quarter
    _Float16* dst = wt + (size_t)e * Uu * Dd + (size_t)(u0 + tu) * Dd + d0 + tq;
    v8h h0, h1;
    #pragma unroll
    for (int j = 0; j < 8; ++j) h0[j] = (_Float16)tile[tq + j][tu];
    #pragma unroll
    for (int j = 0; j < 8; ++j) h1[j] = (_Float16)tile[tq + 8 + j][tu];
    *(v8h*)dst = h0;
    *(v8h*)(dst + 8) = h1;
  }
}

// ---------------------------------------------------------------------------
// Fast GEMM: fp16 inputs, global_load_lds staging, dbuf LDS, 1 barrier/K-tile.
__global__ __launch_bounds__(256) void indexed_dense_gemm_h(
    const _Float16* __restrict__ xh, const _Float16* __restrict__ wt,
    const float* __restrict__ bs, const int* __restrict__ index,
    const int* __restrict__ perm, float* __restrict__ out) {
  const int bx = blockIdx.x;          // n-block 0..31
  const int by = blockIdx.y;          // m-block 0..3
  const int bz = perm[blockIdx.z];    // batch, expert-grouped
  const int e  = index[bz];

  const int tid  = threadIdx.x;
  const int lane = tid & 63;
  const int wave = tid >> 6;

  const _Float16* A  = xh + (size_t)bz * (Ss * Dd) + (size_t)(by * BM) * Dd;
  const _Float16* Bt = wt + (size_t)e * (Dd * Uu) + (size_t)(bx * BN) * Dd;
  const float* bias  = bs + (size_t)e * Uu + bx * BN;
  float*       C     = out + (size_t)bz * (Ss * Uu) + (size_t)(by * BM) * Uu + bx * BN;

  // [m][k] / [n][k], k-contiguous, 64B row pitch, linear (global_load_lds order)
  __shared__ __align__(16) _Float16 As [2][BM * BK];
  __shared__ __align__(16) _Float16 Bsh[2][BN * BK];

  // staging: tile = 512 chunks of 16B; wave w handles chunks [w*64, w*64+64) and +256
  const int c0 = wave * 64;
  auto stage = [&](int buf, int kt) {
    const _Float16* a = A  + kt * BK;
    const _Float16* b = Bt + kt * BK;
    #pragma unroll
    for (int i = 0; i < 2; ++i) {
      const int cb  = c0 + i * 256;       // wave-uniform chunk base
      const int cl  = cb + lane;          // this lane's chunk
      const int row = cl >> 2;            // 4 chunks per 32-half row
      const int kq  = (cl & 3) * 8;
      gl2lds16(a + (size_t)row * Dd + kq, &As [buf][cb * 8]);
      gl2lds16(b + (size_t)row * Dd + kq, &Bsh[buf][cb * 8]);
    }
  };

  // fragment bases (16x16x32 f16: lane holds 8 k-contiguous at k=(lane>>4)*8)
  const int fl = lane & 15;
  const int fq = lane >> 4;
  const int wm = (wave >> 1) * 64;
  const int wn = (wave & 1) * 64;
  const int aOff = (wm + fl) * BK + fq * 8;
  const int bOff = (wn + fl) * BK + fq * 8;

  v4f acc[4][4];
  #pragma unroll
  for (int i = 0; i < 4; ++i)
    #pragma unroll
    for (int j = 0; j < 4; ++j) acc[i][j] = {0.f, 0.f, 0.f, 0.f};

  stage(0, 0);
  __syncthreads();

  int buf = 0;
  for (int kt = 0; kt < KT; ++kt) {
    if (kt + 1 < KT) stage(buf ^ 1, kt + 1);   // async prefetch next tile

    v8h afr[4], bfr[4];
    #pragma unroll
    for (int mt = 0; mt < 4; ++mt) afr[mt] = *(const v8h*)&As [buf][aOff + mt * 16 * BK];
    #pragma unroll
    for (int nt = 0; nt < 4; ++nt) bfr[nt] = *(const v8h*)&Bsh[buf][bOff + nt * 16 * BK];

    #pragma unroll
    for (int mt = 0; mt < 4; ++mt)
      #pragma unroll
      for (int nt = 0; nt < 4; ++nt)
        acc[mt][nt] = __builtin_amdgcn_mfma_f32_16x16x32_f16(afr[mt], bfr[nt], acc[mt][nt], 0, 0, 0);

    if (kt + 1 < KT) {
      __syncthreads();   // vmcnt(0)+lgkmcnt(0) drain: next tile staged, reads done
      buf ^= 1;
    }
  }

  // epilogue: bias + relu.  C/D layout: col=lane&15, row=quad*4+reg.
  float bv[4];
  #pragma unroll
  for (int nt = 0; nt < 4; ++nt) bv[nt] = bias[wn + nt * 16 + fl];

  const int row0 = wm + fq * 4;
  #pragma unroll
  for (int mt = 0; mt < 4; ++mt) {
    #pragma unroll
    for (int r = 0; r < 4; ++r) {
      float* crow = C + (size_t)(row0 + mt * 16 + r) * Uu + wn + fl;
      #pragma unroll
      for (int nt = 0; nt < 4; ++nt) {
        const float v = acc[mt][nt][r] + bv[nt];
        crow[nt * 16] = fmaxf(v, 0.0f);
      }
    }
  }
}

// ---------------------------------------------------------------------------
// Fallback: previous kernel (reg-staged, in-loop fp32->fp16) — used only if
// the workspace is too small for the converted copies.
__global__ __launch_bounds__(256) void indexed_dense_gemm(
    const float* __restrict__ x, const float* __restrict__ ws,
    const float* __restrict__ bs, const int* __restrict__ index,
    const int* __restrict__ perm, float* __restrict__ out) {
  const int bx = blockIdx.x;
  const int by = blockIdx.y;
  const int bz = perm[blockIdx.z];
  const int e  = index[bz];

  const int tid  = threadIdx.x;
  const int lane = tid & 63;
  const int wave = tid >> 6;

  const float* A    = x   + (size_t)bz * (Ss * Dd) + (size_t)(by * BM) * Dd;
  const float* W    = ws  + (size_t)e * (Dd * Uu) + bx * BN;
  const float* bias = bs  + (size_t)e * Uu + bx * BN;
  float*       C    = out + (size_t)bz * (Ss * Uu) + (size_t)(by * BM) * Uu + bx * BN;

  __shared__ __align__(16) _Float16 As[BM * BKP];
  __shared__ __align__(16) _Float16 Bs[BN * BKP];

  const int am  = tid >> 1;
  const int ak0 = (tid & 1) * 16;
  const float* Aptr = A + am * Dd + ak0;
  _Float16* aWr = &As[am * BKP + ak0];

  const int bn  = (wave & 1) * 64 + lane;
  const int bk0 = (wave >> 1) * 16;
  const float* Wptr = W + (size_t)bk0 * Uu + bn;
  _Float16* bWr = &Bs[bn * BKP + bk0];

  const int fl = lane & 15;
  const int fq = lane >> 4;
  const int wm = (wave >> 1) * 64;
  const int wn = (wave & 1) * 64;
  const _Float16* aRd = &As[(wm + fl) * BKP + fq * 8];
  const _Float16* bRd = &Bs[(wn + fl) * BKP + fq * 8];

  v4f acc[4][4];
  #pragma unroll
  for (int i = 0; i < 4; ++i)
    #pragma unroll
    for (int j = 0; j < 4; ++j) acc[i][j] = {0.f, 0.f, 0.f, 0.f};

  v4f   aReg[4];
  float bReg[16];

  auto loadTile = [&](int kt) {
    const float* p = Aptr + kt * BK;
    #pragma unroll
    for (int i = 0; i < 4; ++i) aReg[i] = ((const v4f*)p)[i];
    const float* q = Wptr + (size_t)kt * (BK * Uu);
    #pragma unroll
    for (int j = 0; j < 16; ++j) bReg[j] = q[(size_t)j * Uu];
  };

  auto stage = [&]() {
    union { v8h v[2]; v2fp h[8]; } ua;
    const float* af = (const float*)aReg;
    #pragma unroll
    for (int i = 0; i < 8; ++i)
      ua.h[i] = __builtin_amdgcn_cvt_pkrtz(af[2 * i], af[2 * i + 1]);
    *(v8h*)(aWr)     = ua.v[0];
    *(v8h*)(aWr + 8) = ua.v[1];

    union { v8h v[2]; v2fp h[8]; } ub;
    #pragma unroll
    for (int i = 0; i < 8; ++i)
      ub.h[i] = __builtin_amdgcn_cvt_pkrtz(bReg[2 * i], bReg[2 * i + 1]);
    *(v8h*)(bWr)     = ub.v[0];
    *(v8h*)(bWr + 8) = ub.v[1];
  };

  loadTile(0);
  stage();
  __syncthreads();

  for (int kt = 0; kt < KT; ++kt) {
    if (kt + 1 < KT) loadTile(kt + 1);

    v8h afr[4], bfr[4];
    #pragma unroll
    for (int mt = 0; mt < 4; ++mt) afr[mt] = *(const v8h*)(aRd + mt * 16 * BKP);
    #pragma unroll
    for (int nt = 0; nt < 4; ++nt) bfr[nt] = *(const v8h*)(bRd + nt * 16 * BKP);

    #pragma unroll
    for (int mt = 0; mt < 4; ++mt)
      #pragma unroll
      for (int nt = 0; nt < 4; ++nt)
        acc[mt][nt] = __builtin_amdgcn_mfma_f32_16x16x32_f16(afr[mt], bfr[nt], acc[mt][nt], 0, 0, 0);

    __syncthreads();
    if (kt + 1 < KT) stage();
    __syncthreads();
  }

  float bv[4];
  #pragma unroll
  for (int nt = 0; nt < 4; ++nt) bv[nt] = bias[wn + nt * 16 + fl];

  const int row0 = wm + fq * 4;
  #pragma unroll
  for (int mt = 0; mt < 4; ++mt) {
    #pragma unroll
    for (int r = 0; r < 4; ++r) {
      float* crow = C + (size_t)(row0 + mt * 16 + r) * Uu + wn + fl;
      #pragma unroll
      for (int nt = 0; nt < 4; ++nt) {
        const float v = acc[mt][nt][r] + bv[nt];
        crow[nt * 16] = fmaxf(v, 0.0f);
      }
    }
  }
}

// ---------------------------------------------------------------------------
extern "C" void kernel_launch(void* const* d_in, const int* in_sizes, int n_in,
                              void* d_out, int out_size, void* d_ws, size_t ws_size,
                              hipStream_t stream) {
  const float* x    = (const float*)d_in[0];
  const float* wsP  = (const float*)d_in[1];
  const float* bsP  = (const float*)d_in[2];
  const int*   idx  = (const int*)d_in[3];
  float*       out  = (float*)d_out;

  const size_t szW  = (size_t)Ee * Dd * Uu * sizeof(_Float16);  // 128 MiB
  const size_t szX  = (size_t)Bb * Ss * Dd * sizeof(_Float16);  //  64 MiB
  const size_t need = szW + szX + 1024;

  if (ws_size >= need) {
    _Float16* wt  = (_Float16*)d_ws;
    _Float16* xh  = (_Float16*)((char*)d_ws + szW);
    int* perm = (int*)((char*)d_ws + szW + szX);
    int* used = perm + Bb;

    perm_kernel<<<1, 64, 0, stream>>>(idx, perm, used);
    convert_x<<<(Bb * Ss * Dd) / (256 * 8), 256, 0, stream>>>(x, xh);
    transpose_w<<<dim3(Uu / 64, Dd / 64, Ee), 256, 0, stream>>>(wsP, wt, used);

    dim3 grid(Uu / BN, Ss / BM, Bb);
    indexed_dense_gemm_h<<<grid, 256, 0, stream>>>(xh, wt, bsP, idx, perm, out);
  } else {
    int* perm = (int*)d_ws;
    perm_kernel<<<1, 64, 0, stream>>>(idx, perm, nullptr);
    dim3 grid(Uu / BN, Ss / BM, Bb);
    indexed_dense_gemm<<<grid, 256, 0, stream>>>(x, wsP, bsP, idx, perm, out);
  }
}

// Round 2
// 1016.453 us; speedup vs baseline: 1.3960x; 1.1277x over previous
//
#include <hip/hip_runtime.h>

// IndexedDense: out[b] = relu(x[b] @ ws[idx[b]] + bs[idx[b]])
// B=64, S=512, D=1024, U=4096, E=16.  fp32 in/out, fp16 MFMA internally.
//
// Pipeline:
//   1. perm_kernel : sort batches by expert (L2 locality) + used-expert mask
//   2. convert_x   : x fp32 -> fp16
//   3. transpose_w : ws[e][d][u] fp32 -> wt[e][u][d] fp16 (B k-contiguous)
//   4. gemm_8p     : 256x256 tile, BK=64, 8 waves, 8-phase schedule:
//                    counted vmcnt(2), raw s_barrier, XOR-swizzled LDS,
//                    setprio(1) around MFMA clusters, global_load_lds staging.
// Fallbacks: round-1 2-phase fp16 kernel (if 128KiB LDS attr fails),
//            fp32 reg-staged kernel (if workspace too small).

typedef float v4f  __attribute__((ext_vector_type(4)));
typedef _Float16 v8h __attribute__((ext_vector_type(8)));
typedef __fp16  v2fp __attribute__((ext_vector_type(2)));

constexpr int Bb = 64, Ss = 512, Dd = 1024, Uu = 4096, Ee = 16;

// ---------------------------------------------------------------------------
typedef const __attribute__((address_space(1))) void gvoid_t;
typedef __attribute__((address_space(3))) void lvoid_t;
__device__ __forceinline__ void gl2lds16(const void* g, void* l) {
  __builtin_amdgcn_global_load_lds((gvoid_t*)g, (lvoid_t*)l, 16, 0, 0);
}

#define BAR()  asm volatile("s_barrier" ::: "memory")
#define LGK0() asm volatile("s_waitcnt lgkmcnt(0)" ::: "memory")
#define VMW(n) asm volatile("s_waitcnt vmcnt(" #n ")" ::: "memory")

// ---------------------------------------------------------------------------
__global__ void perm_kernel(const int* __restrict__ index, int* __restrict__ perm,
                            int* __restrict__ used) {
  const int b = threadIdx.x;        // 64 threads
  const int e = index[b];
  int pos = 0;
  for (int b2 = 0; b2 < Bb; ++b2) {
    const int e2 = index[b2];
    pos += (e2 < e) || (e2 == e && b2 < b);
  }
  perm[pos] = b;
  if (used != nullptr && b < Ee) {
    int u = 0;
    for (int b2 = 0; b2 < Bb; ++b2) u |= (index[b2] == b) ? 1 : 0;
    used[b] = u;
  }
}

// ---------------------------------------------------------------------------
__global__ __launch_bounds__(256) void convert_x(const float* __restrict__ in,
                                                 _Float16* __restrict__ outh) {
  const size_t i = ((size_t)blockIdx.x * 256 + threadIdx.x) * 8;
  const v4f a = *(const v4f*)(in + i);
  const v4f b = *(const v4f*)(in + i + 4);
  v8h h;
  #pragma unroll
  for (int j = 0; j < 4; ++j) h[j] = (_Float16)a[j];
  #pragma unroll
  for (int j = 0; j < 4; ++j) h[4 + j] = (_Float16)b[j];
  *(v8h*)(outh + i) = h;
}

// ---------------------------------------------------------------------------
__global__ __launch_bounds__(256) void transpose_w(const float* __restrict__ ws,
                                                   _Float16* __restrict__ wt,
                                                   const int* __restrict__ used) {
  const int e = blockIdx.z;
  if (!used[e]) return;
  const int u0 = blockIdx.x * 64;
  const int d0 = blockIdx.y * 64;
  __shared__ float tile[64][65];
  const int tid = threadIdx.x;
  {
    const int tu = (tid & 15) * 4;
    const int td = tid >> 4;
    const float* src = ws + (size_t)e * Dd * Uu + (size_t)d0 * Uu + u0;
    #pragma unroll
    for (int i = 0; i < 4; ++i) {
      const v4f v = *(const v4f*)(src + (size_t)(td + i * 16) * Uu + tu);
      tile[td + i * 16][tu + 0] = v[0];
      tile[td + i * 16][tu + 1] = v[1];
      tile[td + i * 16][tu + 2] = v[2];
      tile[td + i * 16][tu + 3] = v[3];
    }
  }
  __syncthreads();
  {
    const int tu = tid >> 2;
    const int tq = (tid & 3) * 16;
    _Float16* dst = wt + (size_t)e * Uu * Dd + (size_t)(u0 + tu) * Dd + d0 + tq;
    v8h h0, h1;
    #pragma unroll
    for (int j = 0; j < 8; ++j) h0[j] = (_Float16)tile[tq + j][tu];
    #pragma unroll
    for (int j = 0; j < 8; ++j) h1[j] = (_Float16)tile[tq + 8 + j][tu];
    *(v8h*)dst = h0;
    *(v8h*)(dst + 8) = h1;
  }
}

// ---------------------------------------------------------------------------
// 8-phase 256x256 GEMM.  8 waves (2M x 4N); each wave owns 128x64 output.
// LDS (halves): A[buf] at {0,16384}, B[buf] at {32768,49152}; 128 KiB total.
// LDS row = 64 halves (128 B); 16B-slot s of row r holds global k-slot s^(r&7).
__global__ __launch_bounds__(512, 2) void gemm_8p(
    const _Float16* __restrict__ xh, const _Float16* __restrict__ wt,
    const float* __restrict__ bs, const int* __restrict__ index,
    const int* __restrict__ perm, float* __restrict__ out) {
  extern __shared__ _Float16 lds[];
  constexpr int A0 = 0, A1 = 16384, B0 = 32768, B1 = 49152;
  constexpr int NIT = 8;            // 16 K-steps of BK=64, 2 per iteration

  const int bx = blockIdx.x;        // n-block 0..15
  const int by = blockIdx.y;        // m-block 0..1
  const int bz = perm[blockIdx.z];
  const int e  = index[bz];

  const int tid  = threadIdx.x;
  const int lane = tid & 63;
  const int wave = tid >> 6;
  const int wr = wave >> 2, wc = wave & 3;   // 2 x 4 wave grid
  const int fl = lane & 15, fq = lane >> 4;

  const _Float16* Ag = xh + ((size_t)bz * Ss + by * 256) * Dd;
  const _Float16* Bg = wt + ((size_t)e  * Uu + bx * 256) * Dd;
  const float* bias  = bs + (size_t)e * Uu + bx * 256;
  float* C = out + (size_t)bz * Ss * Uu + (size_t)(by * 256) * Uu + bx * 256;

  // stage one half-tile (128 rows x 64 halves = 1024 x 16B chunks, 2/thread)
  auto stageHT = [&](int ldsBase, const _Float16* g, int half) {
    #pragma unroll
    for (int i = 0; i < 2; ++i) {
      const int cb = i * 512 + wave * 64;       // wave-uniform chunk base
      const int c  = cb + lane;
      const int r  = half * 128 + (c >> 3);
      const int sc = (c & 7) ^ (r & 7);         // inverse swizzle on source
      gl2lds16(g + (size_t)r * Dd + sc * 8, &lds[ldsBase + half * 8192 + cb * 8]);
    }
  };

  // swizzled fragment k-offsets (halves): slot = (kk*4+fq) ^ (row&7), row&7==fl&7
  const int aswz0 = ((0 + fq) ^ (fl & 7)) * 8;
  const int aswz1 = ((4 + fq) ^ (fl & 7)) * 8;

  v8h ar[4][2];   // current m-half A-frags
  v8h br[4][2];   // all 4 n-frags
  auto ldA = [&](int base, int mh) {
    const int r0 = wr * 128 + mh * 64 + fl;
    #pragma unroll
    for (int mi = 0; mi < 4; ++mi) {
      ar[mi][0] = *(const v8h*)&lds[base + (r0 + mi * 16) * 64 + aswz0];
      ar[mi][1] = *(const v8h*)&lds[base + (r0 + mi * 16) * 64 + aswz1];
    }
  };
  auto ldB = [&](int base, int nh) {
    const int r0 = wc * 64 + nh * 32 + fl;
    #pragma unroll
    for (int nl = 0; nl < 2; ++nl) {
      br[nh * 2 + nl][0] = *(const v8h*)&lds[base + (r0 + nl * 16) * 64 + aswz0];
      br[nh * 2 + nl][1] = *(const v8h*)&lds[base + (r0 + nl * 16) * 64 + aswz1];
    }
  };

  v4f acc[8][4];
  #pragma unroll
  for (int i = 0; i < 8; ++i)
    #pragma unroll
    for (int j = 0; j < 4; ++j) acc[i][j] = {0.f, 0.f, 0.f, 0.f};

  auto mm = [&](int mh, int nh) {
    __builtin_amdgcn_s_setprio(1);
    #pragma unroll
    for (int mi = 0; mi < 4; ++mi)
      #pragma unroll
      for (int nl = 0; nl < 2; ++nl) {
        const int gi = mh * 4 + mi, ni = nh * 2 + nl;
        acc[gi][ni] = __builtin_amdgcn_mfma_f32_16x16x32_f16(ar[mi][0], br[ni][0], acc[gi][ni], 0, 0, 0);
        acc[gi][ni] = __builtin_amdgcn_mfma_f32_16x16x32_f16(ar[mi][1], br[ni][1], acc[gi][ni], 0, 0, 0);
      }
    __builtin_amdgcn_s_setprio(0);
  };

  // prologue: ks0 all 4 half-tiles + ks1 A-h0; wait ks0 (leave ks1Ah0 in flight)
  stageHT(A0, Ag, 0); stageHT(A0, Ag, 1);
  stageHT(B0, Bg, 0); stageHT(B0, Bg, 1);
  stageHT(A1, Ag + 64, 0);
  VMW(2); BAR();

  for (int t = 0; t < NIT; ++t) {
    const _Float16* Ao  = Ag + (2 * t + 1) * 64;   // ks 2t+1 (buf1)
    const _Float16* Bo  = Bg + (2 * t + 1) * 64;
    const _Float16* Ae2 = Ag + (2 * t + 2) * 64;   // ks 2t+2 (buf0)
    const _Float16* Be2 = Bg + (2 * t + 2) * 64;
    const _Float16* Ao3 = Ag + (2 * t + 3) * 64;   // ks 2t+3 (buf1)
    const bool st = (t < NIT - 1);

    // ---- K-step 2t (buf0) ----
    // p0
    ldA(A0, 0); ldB(B0, 0);
    stageHT(A1, Ao, 1);
    BAR(); LGK0(); mm(0, 0); BAR();
    // p1
    ldB(B0, 1);
    stageHT(B1, Bo, 0);
    BAR(); LGK0(); mm(0, 1); BAR();
    // p2
    ldA(A0, 1);
    stageHT(B1, Bo, 1);
    BAR(); LGK0(); mm(1, 0); BAR();
    // p3  (vmcnt gate: ks 2t+1 fully landed before p4 reads buf1)
    if (st) stageHT(A0, Ae2, 0);
    BAR(); LGK0(); mm(1, 1);
    if (st) { VMW(2); } else { VMW(0); }
    BAR();

    // ---- K-step 2t+1 (buf1) ----
    // p4
    ldA(A1, 0); ldB(B1, 0);
    if (st) stageHT(A0, Ae2, 1);
    BAR(); LGK0(); mm(0, 0); BAR();
    // p5
    ldB(B1, 1);
    if (st) stageHT(B0, Be2, 0);
    BAR(); LGK0(); mm(0, 1); BAR();
    // p6
    ldA(A1, 1);
    if (st) stageHT(B0, Be2, 1);
    BAR(); LGK0(); mm(1, 0); BAR();
    // p7  (vmcnt gate: ks 2t+2 fully landed before next p0 reads buf0)
    if (st) stageHT(A1, Ao3, 0);
    BAR(); LGK0(); mm(1, 1);
    if (st) { VMW(2); }
    BAR();
  }

  // epilogue: bias + relu.  C/D layout: col=lane&15, row=quad*4+reg.
  float bv[4];
  #pragma unroll
  for (int ni = 0; ni < 4; ++ni) bv[ni] = bias[wc * 64 + ni * 16 + fl];

  #pragma unroll
  for (int gi = 0; gi < 8; ++gi) {
    #pragma unroll
    for (int r = 0; r < 4; ++r) {
      const int row = wr * 128 + gi * 16 + fq * 4 + r;
      float* crow = C + (size_t)row * Uu + wc * 64 + fl;
      #pragma unroll
      for (int ni = 0; ni < 4; ++ni) {
        const float v = acc[gi][ni][r] + bv[ni];
        crow[ni * 16] = fmaxf(v, 0.0f);
      }
    }
  }
}

// ---------------------------------------------------------------------------
// Fallback A: round-1 2-phase fp16 kernel (used if 128 KiB LDS attr fails).
__global__ __launch_bounds__(256) void indexed_dense_gemm_h(
    const _Float16* __restrict__ xh, const _Float16* __restrict__ wt,
    const float* __restrict__ bs, const int* __restrict__ index,
    const int* __restrict__ perm, float* __restrict__ out) {
  constexpr int BM = 128, BN = 128, BK = 32, KT = Dd / BK;
  const int bx = blockIdx.x;
  const int by = blockIdx.y;
  const int bz = perm[blockIdx.z];
  const int e  = index[bz];

  const int tid  = threadIdx.x;
  const int lane = tid & 63;
  const int wave = tid >> 6;

  const _Float16* A  = xh + (size_t)bz * (Ss * Dd) + (size_t)(by * BM) * Dd;
  const _Float16* Bt = wt + (size_t)e * (Dd * Uu) + (size_t)(bx * BN) * Dd;
  const float* bias  = bs + (size_t)e * Uu + bx * BN;
  float*       C     = out + (size_t)bz * Ss * Uu + (size_t)(by * BM) * Uu + bx * BN;

  __shared__ __align__(16) _Float16 As [2][BM * BK];
  __shared__ __align__(16) _Float16 Bsh[2][BN * BK];

  const int c0 = wave * 64;
  auto stage = [&](int buf, int kt) {
    const _Float16* a = A  + kt * BK;
    const _Float16* b = Bt + kt * BK;
    #pragma unroll
    for (int i = 0; i < 2; ++i) {
      const int cb  = c0 + i * 256;
      const int cl  = cb + lane;
      const int row = cl >> 2;
      const int kq  = (cl & 3) * 8;
      gl2lds16(a + (size_t)row * Dd + kq, &As [buf][cb * 8]);
      gl2lds16(b + (size_t)row * Dd + kq, &Bsh[buf][cb * 8]);
    }
  };

  const int fl = lane & 15;
  const int fq = lane >> 4;
  const int wm = (wave >> 1) * 64;
  const int wn = (wave & 1) * 64;
  const int aOff = (wm + fl) * BK + fq * 8;
  const int bOff = (wn + fl) * BK + fq * 8;

  v4f acc[4][4];
  #pragma unroll
  for (int i = 0; i < 4; ++i)
    #pragma unroll
    for (int j = 0; j < 4; ++j) acc[i][j] = {0.f, 0.f, 0.f, 0.f};

  stage(0, 0);
  __syncthreads();

  int buf = 0;
  for (int kt = 0; kt < KT; ++kt) {
    if (kt + 1 < KT) stage(buf ^ 1, kt + 1);

    v8h afr[4], bfr[4];
    #pragma unroll
    for (int mt = 0; mt < 4; ++mt) afr[mt] = *(const v8h*)&As [buf][aOff + mt * 16 * BK];
    #pragma unroll
    for (int nt = 0; nt < 4; ++nt) bfr[nt] = *(const v8h*)&Bsh[buf][bOff + nt * 16 * BK];

    #pragma unroll
    for (int mt = 0; mt < 4; ++mt)
      #pragma unroll
      for (int nt = 0; nt < 4; ++nt)
        acc[mt][nt] = __builtin_amdgcn_mfma_f32_16x16x32_f16(afr[mt], bfr[nt], acc[mt][nt], 0, 0, 0);

    if (kt + 1 < KT) {
      __syncthreads();
      buf ^= 1;
    }
  }

  float bv[4];
  #pragma unroll
  for (int nt = 0; nt < 4; ++nt) bv[nt] = bias[wn + nt * 16 + fl];

  const int row0 = wm + fq * 4;
  #pragma unroll
  for (int mt = 0; mt < 4; ++mt) {
    #pragma unroll
    for (int r = 0; r < 4; ++r) {
      float* crow = C + (size_t)(row0 + mt * 16 + r) * Uu + wn + fl;
      #pragma unroll
      for (int nt = 0; nt < 4; ++nt) {
        const float v = acc[mt][nt][r] + bv[nt];
        crow[nt * 16] = fmaxf(v, 0.0f);
      }
    }
  }
}

// ---------------------------------------------------------------------------
// Fallback B: fp32-input kernel (workspace too small for fp16 copies).
__global__ __launch_bounds__(256) void indexed_dense_gemm(
    const float* __restrict__ x, const float* __restrict__ ws,
    const float* __restrict__ bs, const int* __restrict__ index,
    const int* __restrict__ perm, float* __restrict__ out) {
  constexpr int BM = 128, BN = 128, BK = 32, KT = Dd / BK, BKP = 40;
  const int bx = blockIdx.x;
  const int by = blockIdx.y;
  const int bz = perm[blockIdx.z];
  const int e  = index[bz];

  const int tid  = threadIdx.x;
  const int lane = tid & 63;
  const int wave = tid >> 6;

  const float* A    = x   + (size_t)bz * (Ss * Dd) + (size_t)(by * BM) * Dd;
  const float* W    = ws  + (size_t)e * (Dd * Uu) + bx * BN;
  const float* bias = bs  + (size_t)e * Uu + bx * BN;
  float*       C    = out + (size_t)bz * Ss * Uu + (size_t)(by * BM) * Uu + bx * BN;

  __shared__ __align__(16) _Float16 As[BM * BKP];
  __shared__ __align__(16) _Float16 Bs[BN * BKP];

  const int am  = tid >> 1;
  const int ak0 = (tid & 1) * 16;
  const float* Aptr = A + am * Dd + ak0;
  _Float16* aWr = &As[am * BKP + ak0];

  const int bn  = (wave & 1) * 64 + lane;
  const int bk0 = (wave >> 1) * 16;
  const float* Wptr = W + (size_t)bk0 * Uu + bn;
  _Float16* bWr = &Bs[bn * BKP + bk0];

  const int fl = lane & 15;
  const int fq = lane >> 4;
  const int wm = (wave >> 1) * 64;
  const int wn = (wave & 1) * 64;
  const _Float16* aRd = &As[(wm + fl) * BKP + fq * 8];
  const _Float16* bRd = &Bs[(wn + fl) * BKP + fq * 8];

  v4f acc[4][4];
  #pragma unroll
  for (int i = 0; i < 4; ++i)
    #pragma unroll
    for (int j = 0; j < 4; ++j) acc[i][j] = {0.f, 0.f, 0.f, 0.f};

  v4f   aReg[4];
  float bReg[16];

  auto loadTile = [&](int kt) {
    const float* p = Aptr + kt * BK;
    #pragma unroll
    for (int i = 0; i < 4; ++i) aReg[i] = ((const v4f*)p)[i];
    const float* q = Wptr + (size_t)kt * (BK * Uu);
    #pragma unroll
    for (int j = 0; j < 16; ++j) bReg[j] = q[(size_t)j * Uu];
  };

  auto stage = [&]() {
    union { v8h v[2]; v2fp h[8]; } ua;
    const float* af = (const float*)aReg;
    #pragma unroll
    for (int i = 0; i < 8; ++i)
      ua.h[i] = __builtin_amdgcn_cvt_pkrtz(af[2 * i], af[2 * i + 1]);
    *(v8h*)(aWr)     = ua.v[0];
    *(v8h*)(aWr + 8) = ua.v[1];

    union { v8h v[2]; v2fp h[8]; } ub;
    #pragma unroll
    for (int i = 0; i < 8; ++i)
      ub.h[i] = __builtin_amdgcn_cvt_pkrtz(bReg[2 * i], bReg[2 * i + 1]);
    *(v8h*)(bWr)     = ub.v[0];
    *(v8h*)(bWr + 8) = ub.v[1];
  };

  loadTile(0);
  stage();
  __syncthreads();

  for (int kt = 0; kt < KT; ++kt) {
    if (kt + 1 < KT) loadTile(kt + 1);

    v8h afr[4], bfr[4];
    #pragma unroll
    for (int mt = 0; mt < 4; ++mt) afr[mt] = *(const v8h*)(aRd + mt * 16 * BKP);
    #pragma unroll
    for (int nt = 0; nt < 4; ++nt) bfr[nt] = *(const v8h*)(bRd + nt * 16 * BKP);

    #pragma unroll
    for (int mt = 0; mt < 4; ++mt)
      #pragma unroll
      for (int nt = 0; nt < 4; ++nt)
        acc[mt][nt] = __builtin_amdgcn_mfma_f32_16x16x32_f16(afr[mt], bfr[nt], acc[mt][nt], 0, 0, 0);

    __syncthreads();
    if (kt + 1 < KT) stage();
    __syncthreads();
  }

  float bv[4];
  #pragma unroll
  for (int nt = 0; nt < 4; ++nt) bv[nt] = bias[wn + nt * 16 + fl];

  const int row0 = wm + fq * 4;
  #pragma unroll
  for (int mt = 0; mt < 4; ++mt) {
    #pragma unroll
    for (int r = 0; r < 4; ++r) {
      float* crow = C + (size_t)(row0 + mt * 16 + r) * Uu + wn + fl;
      #pragma unroll
      for (int nt = 0; nt < 4; ++nt) {
        const float v = acc[mt][nt][r] + bv[nt];
        crow[nt * 16] = fmaxf(v, 0.0f);
      }
    }
  }
}

// ---------------------------------------------------------------------------
extern "C" void kernel_launch(void* const* d_in, const int* in_sizes, int n_in,
                              void* d_out, int out_size, void* d_ws, size_t ws_size,
                              hipStream_t stream) {
  const float* x    = (const float*)d_in[0];
  const float* wsP  = (const float*)d_in[1];
  const float* bsP  = (const float*)d_in[2];
  const int*   idx  = (const int*)d_in[3];
  float*       out  = (float*)d_out;

  const size_t szW  = (size_t)Ee * Dd * Uu * sizeof(_Float16);  // 128 MiB
  const size_t szX  = (size_t)Bb * Ss * Dd * sizeof(_Float16);  //  64 MiB
  const size_t need = szW + szX + 1024;

  static bool bigLds = [] {
    return hipFuncSetAttribute(reinterpret_cast<const void*>(gemm_8p),
                               hipFuncAttributeMaxDynamicSharedMemorySize,
                               131072) == hipSuccess;
  }();

  if (ws_size >= need) {
    _Float16* wt  = (_Float16*)d_ws;
    _Float16* xh  = (_Float16*)((char*)d_ws + szW);
    int* perm = (int*)((char*)d_ws + szW + szX);
    int* used = perm + Bb;

    perm_kernel<<<1, 64, 0, stream>>>(idx, perm, used);
    convert_x<<<(Bb * Ss * Dd) / (256 * 8), 256, 0, stream>>>(x, xh);
    transpose_w<<<dim3(Uu / 64, Dd / 64, Ee), 256, 0, stream>>>(wsP, wt, used);

    if (bigLds) {
      dim3 grid(Uu / 256, Ss / 256, Bb);
      gemm_8p<<<grid, 512, 131072, stream>>>(xh, wt, bsP, idx, perm, out);
    } else {
      dim3 grid(Uu / 128, Ss / 128, Bb);
      indexed_dense_gemm_h<<<grid, 256, 0, stream>>>(xh, wt, bsP, idx, perm, out);
    }
  } else {
    int* perm = (int*)d_ws;
    perm_kernel<<<1, 64, 0, stream>>>(idx, perm, nullptr);
    dim3 grid(Uu / 128, Ss / 128, Bb);
    indexed_dense_gemm<<<grid, 256, 0, stream>>>(x, wsP, bsP, idx, perm, out);
  }
}